// Round 6
// baseline (1488.442 us; speedup 1.0000x reference)
//
#include <hip/hip_runtime.h>

// snn_layer: out[b,u,t] = (sum_f in[b,f,t] * w[f,u] > 1.0f) ? 1.0f : 0.0f
// B=128 F=512 T=256 U=1024, fp32. No fp32 MFMA -> vector FMA, floor 219 us.
//
// R1 (440us): both-LDS 8x8 tile -> port-bound: 4xds_read_b128/wave-k = 192
//     CU-port-cyc vs 128 FMA-cyc -> 66% VALU (model matched measurement).
// R2 (1800us): divergent per-k global A -> latency/L2 thrash.
// R3-R5 (1085/551/486us): SGPR-A variants. Dead end: SMEM is out-of-order ->
//     only lgkmcnt(0) waits work (drains prefetches too), and 128B/wave-k
//     of scalar traffic saturates the shared K$ (~8B/cyc/CU). R4 and R5
//     both pin at ~50% VALU regardless of B path or TLP.
// R6: both-LDS again, micro-tile 16x8 per lane: 6xds_read_b128 (72 port-cyc)
//     per 256 FMA-cyc -> per-CU port 288+~10 staging vs 256 FMA -> 86%
//     ceiling. Fragments split as two half-tiles 64 apart so each read's 8
//     addresses hit distinct bank-quads or 2-way alias (free) -> zero
//     conflicts, layouts stay linear -> DMA staging (R4 drain-before-issue
//     double buffer) works. Block = 4 waves, tile u=128 x t=64, BK=8.

#define FF 512
#define TT 256
#define UU 1024
#define BK 8

__global__ __launch_bounds__(256, 2)
void snn_gemm_r6(const float* __restrict__ in, const float* __restrict__ w,
                 float* __restrict__ out) {
    __shared__ float As[2][BK][128];  // A = w tile  (k-row: u0..u0+127), 8 KB
    __shared__ float Bs[2][BK][64];   // B = in tile (k-row: t0..t0+63),  4 KB

    const int b    = blockIdx.z;
    const int u0   = blockIdx.y * 128;
    const int t0   = blockIdx.x * 64;
    const int tid  = threadIdx.x;
    const int wv   = tid >> 6;        // wave 0..3
    const int lane = tid & 63;
    const int g    = lane >> 3;       // m-group 0..7 (16 u-rows: g*8 & 64+g*8)
    const int h    = lane & 7;        // n-group 0..7 (8 t-cols: h*4 & 32+h*4)

    const float* __restrict__ inb = in + (size_t)b * FF * TT;

    float acc[16][8];
#pragma unroll
    for (int i = 0; i < 16; i++)
#pragma unroll
        for (int j = 0; j < 8; j++) acc[i][j] = 0.0f;

    // --- staging helpers (DMA: LDS dst must be wave-uniform base + 16*lane) ---
    // A: wave wv stages k-rows {2wv, 2wv+1}: lane L -> w[f+2wv+(L>>5)][u0+(L&31)*4]
    // B: waves 0,1 stage k-rows {4wv..4wv+3}: lane L -> in[f+4wv+(L>>4)][t0+(L&15)*4]
#define STAGE(fn, buf)                                                          \
    do {                                                                        \
        __builtin_amdgcn_global_load_lds(                                       \
            (const __attribute__((address_space(1))) void*)                     \
                (w + (size_t)((fn) + 2 * wv + (lane >> 5)) * UU + u0 +          \
                 (lane & 31) * 4),                                              \
            (__attribute__((address_space(3))) void*)&As[buf][2 * wv][0],       \
            16, 0, 0);                                                          \
        if (wv < 2) {                                                           \
            __builtin_amdgcn_global_load_lds(                                   \
                (const __attribute__((address_space(1))) void*)                 \
                    (inb + (size_t)((fn) + 4 * wv + (lane >> 4)) * TT + t0 +    \
                     (lane & 15) * 4),                                          \
                (__attribute__((address_space(3))) void*)&Bs[buf][4 * wv][0],   \
                16, 0, 0);                                                      \
        }                                                                       \
    } while (0)

    STAGE(0, 0);

    for (int f0 = 0; f0 < FF; f0 += BK) {
        const int buf = (f0 / BK) & 1;

        // Drains this buffer's DMA (issued one full tile ago -> ~free) and
        // protects buf^1; next tile's DMA is issued only AFTER the drain.
        __syncthreads();

        if (f0 + BK < FF) STAGE(f0 + BK, buf ^ 1);

#pragma unroll
        for (int k = 0; k < BK; k++) {
            // A frag: 16 u-values as two half-tiles (addresses g*32B(+16)
            // and 256B+g*32B(+16): 8 addrs/instr, 2-way alias only -> free).
            const float4 a0 = *(const float4*)&As[buf][k][g * 8];
            const float4 a1 = *(const float4*)&As[buf][k][g * 8 + 4];
            const float4 a2 = *(const float4*)&As[buf][k][64 + g * 8];
            const float4 a3 = *(const float4*)&As[buf][k][64 + g * 8 + 4];
            // B frag: 8 t-values as two quads 32 apart (addrs h*16B, 128+h*16B
            // -> 8 distinct bank-quads, broadcast over g -> conflict-free).
            const float4 b0 = *(const float4*)&Bs[buf][k][h * 4];
            const float4 b1 = *(const float4*)&Bs[buf][k][32 + h * 4];

            const float am[16] = {a0.x, a0.y, a0.z, a0.w, a1.x, a1.y, a1.z, a1.w,
                                  a2.x, a2.y, a2.z, a2.w, a3.x, a3.y, a3.z, a3.w};
            const float bn[8]  = {b0.x, b0.y, b0.z, b0.w, b1.x, b1.y, b1.z, b1.w};
#pragma unroll
            for (int i = 0; i < 16; i++)
#pragma unroll
                for (int j = 0; j < 8; j++)
                    acc[i][j] = fmaf(am[i], bn[j], acc[i][j]);
        }
    }

    // Epilogue: heaviside(h - 1) == (h > 1.0f), exact in fp32.
    // Lane's u-rows: u0+g*8+i and u0+64+g*8+i; t-chunks t0+h*4, t0+32+h*4
    // (consecutive h -> consecutive 16B -> coalesced 128B runs per g-group).
#pragma unroll
    for (int i = 0; i < 16; i++) {
        const int u = u0 + ((i < 8) ? (g * 8 + i) : (64 + g * 8 + i - 8));
        float* __restrict__ orow = out + ((size_t)b * UU + u) * TT + t0;
        float4 lo, hi;
        lo.x = acc[i][0] > 1.0f ? 1.0f : 0.0f;
        lo.y = acc[i][1] > 1.0f ? 1.0f : 0.0f;
        lo.z = acc[i][2] > 1.0f ? 1.0f : 0.0f;
        lo.w = acc[i][3] > 1.0f ? 1.0f : 0.0f;
        hi.x = acc[i][4] > 1.0f ? 1.0f : 0.0f;
        hi.y = acc[i][5] > 1.0f ? 1.0f : 0.0f;
        hi.z = acc[i][6] > 1.0f ? 1.0f : 0.0f;
        hi.w = acc[i][7] > 1.0f ? 1.0f : 0.0f;
        *(float4*)&orow[h * 4]      = lo;
        *(float4*)&orow[32 + h * 4] = hi;
    }
}

extern "C" void kernel_launch(void* const* d_in, const int* in_sizes, int n_in,
                              void* d_out, int out_size, void* d_ws, size_t ws_size,
                              hipStream_t stream) {
    const float* in = (const float*)d_in[0];  // [128,512,256]
    const float* w  = (const float*)d_in[1];  // [512,1024]
    float* out      = (float*)d_out;          // [128,1024,256]

    dim3 grid(TT / 64, UU / 128, 128);  // (4, 8, 128) = 4096 blocks
    snn_gemm_r6<<<grid, dim3(256), 0, stream>>>(in, w, out);
}